// Round 3
// baseline (600.328 us; speedup 1.0000x reference)
//
#include <hip/hip_runtime.h>
#include <stdint.h>
#include <stddef.h>

// snnLinear: FWHT -> A4 global asym fake-quant -> W4 per-row sym fake-quant
// -> linear. Strategy: exact integer reformulation; GEMM runs on i8 MFMA.
//
// out[m,n] = sx*sw[n] * sum_k (qx[m,k]-zp)*(qw[n,k]) + bias[n]
//
// Quantization path is bitwise-identical to the JAX reference (same FWHT
// stage order stride 2048->1, IEEE divs, rintf==jnp.round).

typedef __attribute__((ext_vector_type(4))) int int4v;
typedef __attribute__((ext_vector_type(4))) float float4v;

#define EPSQ 1e-8f
// pad 8 dwords per 256 dwords: pad tracks bit 8, so FWHT phase-2's hi=t>>4
// axis spreads across banks {0,8,16,24}. Worst-case aliasing in all phases
// is 2-way (free, m136). 16-dword chunks stay contiguous + 16B-aligned.
#define PADA(i) ((i) + (((i) >> 8) << 3))

__device__ __forceinline__ unsigned int encf(float f) {
    unsigned int u = __float_as_uint(f);
    return (u & 0x80000000u) ? ~u : (u | 0x80000000u);  // order-preserving
}
__device__ __forceinline__ float decf(unsigned int e) {
    return __uint_as_float((e & 0x80000000u) ? (e ^ 0x80000000u) : ~e);
}

// 4 butterfly stages over 16 in-register values, DESCENDING stride (8,4,2,1)
// to mirror the reference's big-stride-first order.
__device__ __forceinline__ void fwht16(float (&e)[16]) {
#pragma unroll
    for (int s = 8; s >= 1; s >>= 1)
#pragma unroll
        for (int j = 0; j < 16; ++j)
            if ((j & s) == 0) {
                float a = e[j], b = e[j + s];
                e[j] = a + b;
                e[j + s] = a - b;
            }
}

// y = H*x / 64 for one 4096-length row; thread t ends with e[j] = y[t*16+j].
// Stage order: bits 11..8 (phase1), 7..4 (phase2), 3..0 (phase3) == reference.
__device__ __forceinline__ void fwht_row(const float* __restrict__ xrow,
                                         float* lds, float (&e)[16], int t) {
    const float4v* xv = (const float4v*)xrow;
    float4v v0 = xv[t * 4 + 0], v1 = xv[t * 4 + 1],
            v2 = xv[t * 4 + 2], v3 = xv[t * 4 + 3];
    {
        float* dst = lds + PADA(t * 16);
        ((float4v*)dst)[0] = v0; ((float4v*)dst)[1] = v1;
        ((float4v*)dst)[2] = v2; ((float4v*)dst)[3] = v3;
    }
    __syncthreads();

    // phase 1: thread t holds {i : i = j*256 + t}  (strides 2048..256)
    float g[16];
#pragma unroll
    for (int j = 0; j < 16; ++j) g[j] = lds[PADA(j * 256 + t)];
    fwht16(g);
#pragma unroll
    for (int j = 0; j < 16; ++j) lds[PADA(j * 256 + t)] = g[j];
    __syncthreads();

    // phase 2: thread (hi,lo) holds {i = hi*256 + j*16 + lo} (strides 128..16)
    {
        int hi = t >> 4, lo = t & 15;
        float f[16];
#pragma unroll
        for (int j = 0; j < 16; ++j) f[j] = lds[PADA(hi * 256 + j * 16 + lo)];
        fwht16(f);
#pragma unroll
        for (int j = 0; j < 16; ++j) lds[PADA(hi * 256 + j * 16 + lo)] = f[j];
    }
    __syncthreads();

    // phase 3: thread t holds 16 consecutive {i = t*16 + j} (strides 8..1)
    {
        float* src = lds + PADA(t * 16);
        float4v w0 = ((float4v*)src)[0], w1 = ((float4v*)src)[1],
                w2 = ((float4v*)src)[2], w3 = ((float4v*)src)[3];
#pragma unroll
        for (int q = 0; q < 4; ++q) {
            e[q] = w0[q]; e[4 + q] = w1[q]; e[8 + q] = w2[q]; e[12 + q] = w3[q];
        }
    }
    fwht16(e);
#pragma unroll
    for (int j = 0; j < 16; ++j) e[j] *= 0.015625f;  // 1/sqrt(4096), exact
}

__global__ void k_init(unsigned int* mm) {
    mm[0] = 0xFFFFFFFFu;  // encoded-min init (largest key)
    mm[1] = 0u;           // encoded-max init (smallest key)
}

__global__ __launch_bounds__(256) void k_fwht_minmax(
    const float* __restrict__ x, unsigned int* __restrict__ mm) {
    __shared__ float lds[4224];
    __shared__ float red[8];
    int row = blockIdx.x, t = threadIdx.x;
    float e[16];
    fwht_row(x + (size_t)row * 4096, lds, e, t);

    float mn = e[0], mx = e[0];
#pragma unroll
    for (int j = 1; j < 16; ++j) { mn = fminf(mn, e[j]); mx = fmaxf(mx, e[j]); }
#pragma unroll
    for (int m = 32; m >= 1; m >>= 1) {
        mn = fminf(mn, __shfl_xor(mn, m));
        mx = fmaxf(mx, __shfl_xor(mx, m));
    }
    int wid = t >> 6;
    if ((t & 63) == 0) { red[wid * 2] = mn; red[wid * 2 + 1] = mx; }
    __syncthreads();
    if (t == 0) {
#pragma unroll
        for (int wv = 1; wv < 4; ++wv) {
            mn = fminf(mn, red[wv * 2]);
            mx = fmaxf(mx, red[wv * 2 + 1]);
        }
        atomicMin(mm + 0, encf(mn));
        atomicMax(mm + 1, encf(mx));
    }
}

__global__ __launch_bounds__(256) void k_quant_x(
    const float* __restrict__ x, const unsigned int* __restrict__ mm,
    int8_t* __restrict__ xq) {
    __shared__ float lds[4224];
    int row = blockIdx.x, t = threadIdx.x;
    float e[16];
    fwht_row(x + (size_t)row * 4096, lds, e, t);

    float xmin = decf(mm[0]), xmax = decf(mm[1]);
    float scale = fmaxf((xmax - xmin) / 15.0f, EPSQ);
    float zp = rintf(-xmin / scale);
    int izp = (int)zp;

    union { signed char c[16]; int4v v; } pk;
#pragma unroll
    for (int j = 0; j < 16; ++j) {
        float q = rintf(e[j] / scale) + zp;
        q = fminf(fmaxf(q, 0.0f), 15.0f);
        pk.c[j] = (signed char)((int)q - izp);  // in [-15,15]
    }
    *(int4v*)(xq + (size_t)row * 4096 + t * 16) = pk.v;
}

__global__ __launch_bounds__(256) void k_quant_w(
    const float* __restrict__ w, int8_t* __restrict__ wq,
    float* __restrict__ sw) {
    __shared__ float red[4];
    int o = blockIdx.x, t = threadIdx.x;
    const float4v* wv = (const float4v*)(w + (size_t)o * 4096);
    float4v a0 = wv[t * 4 + 0], a1 = wv[t * 4 + 1],
            a2 = wv[t * 4 + 2], a3 = wv[t * 4 + 3];
    float vals[16];
#pragma unroll
    for (int q = 0; q < 4; ++q) {
        vals[q] = a0[q]; vals[4 + q] = a1[q];
        vals[8 + q] = a2[q]; vals[12 + q] = a3[q];
    }
    float am = 0.0f;
#pragma unroll
    for (int j = 0; j < 16; ++j) am = fmaxf(am, fabsf(vals[j]));
#pragma unroll
    for (int m = 32; m >= 1; m >>= 1) am = fmaxf(am, __shfl_xor(am, m));
    if ((t & 63) == 0) red[t >> 6] = am;
    __syncthreads();
    am = fmaxf(fmaxf(red[0], red[1]), fmaxf(red[2], red[3]));

    float scale = fmaxf(am / 7.0f, EPSQ);
    if (t == 0) sw[o] = scale;

    union { signed char c[16]; int4v v; } pk;
#pragma unroll
    for (int j = 0; j < 16; ++j) {
        float q = rintf(vals[j] / scale);
        q = fminf(fmaxf(q, -8.0f), 7.0f);
        pk.c[j] = (signed char)(int)q;
    }
    *(int4v*)(wq + (size_t)o * 4096 + t * 16) = pk.v;
}

// ---------------- i8 GEMM, m97 structure: 128x128 tile, BK=64, 4 waves ----
#define BM 128
#define BN 128
#define BKq 64

__global__ __launch_bounds__(256) void k_gemm(
    const int8_t* __restrict__ A,   // [8192][4096] qx-zp
    const int8_t* __restrict__ B,   // [4096][4096] qw (N x K)
    const float* __restrict__ sw, const float* __restrict__ bias,
    const unsigned int* __restrict__ mm, float* __restrict__ C) {
    constexpr int N = 4096, K = 4096;
    __shared__ __align__(16) int8_t As[BM * BKq];
    __shared__ __align__(16) int8_t Bs[BN * BKq];

    int tid = threadIdx.x;
    int m0 = (blockIdx.x >> 5) * BM;
    int n0 = (blockIdx.x & 31) * BN;
    int w = tid >> 6, l = tid & 63;
    int wr = w >> 1, wc = w & 1;       // wave -> 64x64 quadrant
    int kg = l >> 4, lr = l & 15;

    int4v acc[4][4] = {};

    for (int k0 = 0; k0 < K; k0 += BKq) {
#pragma unroll
        for (int it = 0; it < 2; ++it) {
            int idx = it * 256 + tid;
            int row = idx >> 2, cc = idx & 3;
            __builtin_amdgcn_global_load_lds(
                (const __attribute__((address_space(1))) void*)
                    (A + (size_t)(m0 + row) * K + k0 + cc * 16),
                (__attribute__((address_space(3))) void*)(As + idx * 16),
                16, 0, 0);
            __builtin_amdgcn_global_load_lds(
                (const __attribute__((address_space(1))) void*)
                    (B + (size_t)(n0 + row) * K + k0 + cc * 16),
                (__attribute__((address_space(3))) void*)(Bs + idx * 16),
                16, 0, 0);
        }
        __syncthreads();

        int4v af[4], bf[4];
#pragma unroll
        for (int i = 0; i < 4; ++i) {
            af[i] = *(const int4v*)(As + (wr * 64 + i * 16 + lr) * BKq + kg * 16);
            bf[i] = *(const int4v*)(Bs + (wc * 64 + i * 16 + lr) * BKq + kg * 16);
        }
#pragma unroll
        for (int i = 0; i < 4; ++i)
#pragma unroll
            for (int j = 0; j < 4; ++j)
                acc[i][j] = __builtin_amdgcn_mfma_i32_16x16x64_i8(
                    af[i], bf[j], acc[i][j], 0, 0, 0);
        __syncthreads();
    }

    float xmin = decf(mm[0]), xmax = decf(mm[1]);
    float sx = fmaxf((xmax - xmin) / 15.0f, EPSQ);

#pragma unroll
    for (int j = 0; j < 4; ++j) {
        int col = n0 + wc * 64 + j * 16 + lr;
        float s = sx * sw[col];
        float bz = bias[col];
#pragma unroll
        for (int i = 0; i < 4; ++i) {
            int rowb = m0 + wr * 64 + i * 16 + kg * 4;
#pragma unroll
            for (int r = 0; r < 4; ++r)
                C[(size_t)(rowb + r) * N + col] =
                    (float)acc[i][j][r] * s + bz;
        }
    }
}

extern "C" void kernel_launch(void* const* d_in, const int* in_sizes, int n_in,
                              void* d_out, int out_size, void* d_ws,
                              size_t ws_size, hipStream_t stream) {
    const float* x = (const float*)d_in[0];       // [4,2048,4096]
    const float* weight = (const float*)d_in[1];  // [4096,4096]
    const float* bias = (const float*)d_in[2];    // [4096]
    float* out = (float*)d_out;

    char* ws = (char*)d_ws;
    unsigned int* mm = (unsigned int*)ws;                       // 8 B
    float* sw = (float*)(ws + 1024);                            // 16 KB
    int8_t* xq = (int8_t*)(ws + 65536);                         // 32 MB
    int8_t* wq = (int8_t*)(ws + 65536 + (size_t)8192 * 4096);   // 16 MB

    hipLaunchKernelGGL(k_init, dim3(1), dim3(1), 0, stream, mm);
    hipLaunchKernelGGL(k_fwht_minmax, dim3(8192), dim3(256), 0, stream, x, mm);
    hipLaunchKernelGGL(k_quant_w, dim3(4096), dim3(256), 0, stream, weight, wq, sw);
    hipLaunchKernelGGL(k_quant_x, dim3(8192), dim3(256), 0, stream, x, mm, xq);
    hipLaunchKernelGGL(k_gemm, dim3(64 * 32), dim3(256), 0, stream,
                       xq, wq, sw, bias, mm, out);
}

// Round 6
// 479.716 us; speedup vs baseline: 1.2514x; 1.2514x over previous
//
#include <hip/hip_runtime.h>
#include <stdint.h>
#include <stddef.h>

// snnLinear: FWHT -> A4 global asym fake-quant -> W4 per-row sym fake-quant
// -> linear.  out[m,n] = sx*sw[n] * sum_k (qx-zp)*qw + bias[n], exact in i32.
//
// R3 lesson: LDS passed as generic float* => private arrays forced to
// scratch (VGPR=12, 197us, all pipes idle). This version: FWHT is
// wave-per-row, register-only, shfl_xor cross-lane. No LDS in hot kernels.

typedef __attribute__((ext_vector_type(4))) int int4v;
typedef __attribute__((ext_vector_type(4))) float float4v;

#define EPSQ 1e-8f

// lane l holds e[j] = row[(j>>2)*256 + l*4 + (j&3)], j=0..63.
// Reference stage order (element stride 2048 -> 1) maps to:
//   i-bits 11..8 : in-register j-strides 32,16,8,4
//   i-bits 7..2  : cross-lane shfl_xor masks 32,16,8,4,2,1
//   i-bits 1..0  : in-register j-strides 2,1
// Butterfly fmaf(+1,a,b)=a+b / fmaf(-1,b,a)=a-b is bitwise IEEE-identical.
__device__ __forceinline__ void fwht_wave(float (&e)[64], int l) {
#pragma unroll
    for (int s = 32; s >= 4; s >>= 1)
#pragma unroll
        for (int j = 0; j < 64; ++j)
            if ((j & s) == 0) {
                float a = e[j], b = e[j + s];
                e[j] = a + b;
                e[j + s] = a - b;
            }
#pragma unroll
    for (int m = 32; m >= 1; m >>= 1) {
        float sgn = (l & m) ? -1.0f : 1.0f;
#pragma unroll
        for (int j = 0; j < 64; ++j) {
            float t = __shfl_xor(e[j], m);
            e[j] = fmaf(sgn, e[j], t);
        }
    }
#pragma unroll
    for (int s = 2; s >= 1; s >>= 1)
#pragma unroll
        for (int j = 0; j < 64; ++j)
            if ((j & s) == 0) {
                float a = e[j], b = e[j + s];
                e[j] = a + b;
                e[j + s] = a - b;
            }
}

__device__ __forceinline__ void load_row(const float* __restrict__ xr, int l,
                                         float (&e)[64]) {
    const float4v* xv = (const float4v*)xr;
#pragma unroll
    for (int q = 0; q < 16; ++q) {
        float4v v = xv[q * 64 + l];
        e[4 * q + 0] = v[0]; e[4 * q + 1] = v[1];
        e[4 * q + 2] = v[2]; e[4 * q + 3] = v[3];
    }
}

// ---- pass 1: FWHT + per-wave min/max (no y store; recompute in pass 2) ----
__global__ __launch_bounds__(256) void k_fwht_minmax(
    const float* __restrict__ x, float2* __restrict__ wmm) {
    int l = threadIdx.x & 63, w = threadIdx.x >> 6;
    int row = blockIdx.x * 4 + w;
    float e[64];
    load_row(x + (size_t)row * 4096, l, e);
    fwht_wave(e, l);
    float mn = e[0], mx = e[0];
#pragma unroll
    for (int j = 1; j < 64; ++j) { mn = fminf(mn, e[j]); mx = fmaxf(mx, e[j]); }
#pragma unroll
    for (int m = 32; m >= 1; m >>= 1) {
        mn = fminf(mn, __shfl_xor(mn, m));
        mx = fmaxf(mx, __shfl_xor(mx, m));
    }
    // scale AFTER min/max: rounding is monotone, bitwise == min/max of scaled
    if (l == 0) wmm[row] = make_float2(mn * 0.015625f, mx * 0.015625f);
}

// ---- tiny deterministic reduction: 8192 wave-results -> global min/max ----
__global__ __launch_bounds__(256) void k_mmred(const float2* __restrict__ wmm,
                                               float* __restrict__ mm) {
    __shared__ float red[8];
    int t = threadIdx.x;
    float mn = INFINITY, mx = -INFINITY;
    for (int i = t; i < 8192; i += 256) {
        float2 v = wmm[i];
        mn = fminf(mn, v.x);
        mx = fmaxf(mx, v.y);
    }
#pragma unroll
    for (int m = 32; m >= 1; m >>= 1) {
        mn = fminf(mn, __shfl_xor(mn, m));
        mx = fmaxf(mx, __shfl_xor(mx, m));
    }
    if ((t & 63) == 0) { red[(t >> 6) * 2] = mn; red[(t >> 6) * 2 + 1] = mx; }
    __syncthreads();
    if (t == 0) {
#pragma unroll
        for (int wv = 1; wv < 4; ++wv) {
            mn = fminf(mn, red[wv * 2]);
            mx = fmaxf(mx, red[wv * 2 + 1]);
        }
        mm[0] = mn;
        mm[1] = mx;
    }
}

// ---- pass 2: FWHT recompute + quantize to packed i8 codes (q - zp) ----
__global__ __launch_bounds__(256) void k_quant_x(
    const float* __restrict__ x, const float* __restrict__ mm,
    int8_t* __restrict__ xq) {
    int l = threadIdx.x & 63, w = threadIdx.x >> 6;
    int row = blockIdx.x * 4 + w;
    float e[64];
    load_row(x + (size_t)row * 4096, l, e);
    fwht_wave(e, l);

    float xmin = mm[0], xmax = mm[1];
    float scale = fmaxf((xmax - xmin) / 15.0f, EPSQ);
    float zp = rintf(-xmin / scale);
    int izp = (int)zp;

    int* qrow = (int*)(xq + (size_t)row * 4096);
#pragma unroll
    for (int q = 0; q < 16; ++q) {
        int pk = 0;
#pragma unroll
        for (int r = 0; r < 4; ++r) {
            float v = e[4 * q + r] * 0.015625f;
            float qq = rintf(v / scale) + zp;
            qq = fminf(fmaxf(qq, 0.0f), 15.0f);
            int code = (int)qq - izp;  // [-15,15]
            pk |= (code & 0xFF) << (8 * r);
        }
        qrow[q * 64 + l] = pk;  // byte addr row*4096 + q*256 + l*4, coalesced
    }
}

// ---- weight quant: per-row absmax -> scale -> packed i8 ----
__global__ __launch_bounds__(256) void k_quant_w(
    const float* __restrict__ wgt, int8_t* __restrict__ wq,
    float* __restrict__ sw) {
    __shared__ float red[4];
    int o = blockIdx.x, t = threadIdx.x;
    const float4v* wv = (const float4v*)(wgt + (size_t)o * 4096);
    float4v a0 = wv[t * 4 + 0], a1 = wv[t * 4 + 1],
            a2 = wv[t * 4 + 2], a3 = wv[t * 4 + 3];
    float am = 0.0f;
#pragma unroll
    for (int r = 0; r < 4; ++r)
        am = fmaxf(am, fmaxf(fmaxf(fabsf(a0[r]), fabsf(a1[r])),
                             fmaxf(fabsf(a2[r]), fabsf(a3[r]))));
#pragma unroll
    for (int m = 32; m >= 1; m >>= 1) am = fmaxf(am, __shfl_xor(am, m));
    if ((t & 63) == 0) red[t >> 6] = am;
    __syncthreads();
    am = fmaxf(fmaxf(red[0], red[1]), fmaxf(red[2], red[3]));

    float scale = fmaxf(am / 7.0f, EPSQ);
    if (t == 0) sw[o] = scale;

    int4v pk;
#pragma unroll
    for (int k = 0; k < 4; ++k) {
        float4v a = (k == 0) ? a0 : (k == 1) ? a1 : (k == 2) ? a2 : a3;
        int p = 0;
#pragma unroll
        for (int r = 0; r < 4; ++r) {
            float q = rintf(a[r] / scale);
            q = fminf(fmaxf(q, -8.0f), 7.0f);
            p |= ((int)q & 0xFF) << (8 * r);
        }
        pk[k] = p;
    }
    *(int4v*)(wq + (size_t)o * 4096 + t * 16) = pk;
}

// ---------------- i8 GEMM, m97 structure: 128x128 tile, BK=64 bytes -------
#define BM 128
#define BN 128
#define BKq 64

__global__ __launch_bounds__(256) void k_gemm(
    const int8_t* __restrict__ A,   // [8192][4096] qx-zp
    const int8_t* __restrict__ B,   // [4096][4096] qw (N x K)
    const float* __restrict__ sw, const float* __restrict__ bias,
    const float* __restrict__ mm, float* __restrict__ C) {
    constexpr int N = 4096, K = 4096;
    __shared__ __align__(16) int8_t As[BM * BKq];
    __shared__ __align__(16) int8_t Bs[BN * BKq];

    int tid = threadIdx.x;
    int m0 = (blockIdx.x >> 5) * BM;
    int n0 = (blockIdx.x & 31) * BN;
    int w = tid >> 6, l = tid & 63;
    int wr = w >> 1, wc = w & 1;  // wave -> 64x64 quadrant
    int kg = l >> 4, lr = l & 15;

    int4v acc[4][4] = {};

    for (int k0 = 0; k0 < K; k0 += BKq) {
#pragma unroll
        for (int it = 0; it < 2; ++it) {
            int idx = it * 256 + tid;
            int row = idx >> 2, cc = idx & 3;
            __builtin_amdgcn_global_load_lds(
                (const __attribute__((address_space(1))) void*)
                    (A + (size_t)(m0 + row) * K + k0 + cc * 16),
                (__attribute__((address_space(3))) void*)(As + idx * 16),
                16, 0, 0);
            __builtin_amdgcn_global_load_lds(
                (const __attribute__((address_space(1))) void*)
                    (B + (size_t)(n0 + row) * K + k0 + cc * 16),
                (__attribute__((address_space(3))) void*)(Bs + idx * 16),
                16, 0, 0);
        }
        __syncthreads();

        int4v af[4], bf[4];
#pragma unroll
        for (int i = 0; i < 4; ++i) {
            af[i] = *(const int4v*)(As + (wr * 64 + i * 16 + lr) * BKq + kg * 16);
            bf[i] = *(const int4v*)(Bs + (wc * 64 + i * 16 + lr) * BKq + kg * 16);
        }
#pragma unroll
        for (int i = 0; i < 4; ++i)
#pragma unroll
            for (int j = 0; j < 4; ++j)
                acc[i][j] = __builtin_amdgcn_mfma_i32_16x16x64_i8(
                    af[i], bf[j], acc[i][j], 0, 0, 0);
        __syncthreads();
    }

    float xmin = mm[0], xmax = mm[1];
    float sx = fmaxf((xmax - xmin) / 15.0f, EPSQ);

#pragma unroll
    for (int j = 0; j < 4; ++j) {
        int col = n0 + wc * 64 + j * 16 + lr;
        float s = sx * sw[col];
        float bz = bias[col];
#pragma unroll
        for (int i = 0; i < 4; ++i) {
            int rowb = m0 + wr * 64 + i * 16 + kg * 4;
#pragma unroll
            for (int r = 0; r < 4; ++r)
                C[(size_t)(rowb + r) * N + col] =
                    (float)acc[i][j][r] * s + bz;
        }
    }
}

extern "C" void kernel_launch(void* const* d_in, const int* in_sizes, int n_in,
                              void* d_out, int out_size, void* d_ws,
                              size_t ws_size, hipStream_t stream) {
    const float* x = (const float*)d_in[0];       // [4,2048,4096]
    const float* weight = (const float*)d_in[1];  // [4096,4096]
    const float* bias = (const float*)d_in[2];    // [4096]
    float* out = (float*)d_out;

    char* ws = (char*)d_ws;
    float* mm = (float*)ws;                            // 8 B  {min,max}
    float2* wmm = (float2*)(ws + 1024);                // 64 KB per-wave pairs
    float* sw = (float*)(ws + 131072);                 // 16 KB
    int8_t* xq = (int8_t*)(ws + (1 << 20));            // 32 MB
    int8_t* wq = (int8_t*)(ws + (1 << 20) + ((size_t)8192 * 4096));  // 16 MB

    hipLaunchKernelGGL(k_fwht_minmax, dim3(2048), dim3(256), 0, stream, x, wmm);
    hipLaunchKernelGGL(k_mmred, dim3(1), dim3(256), 0, stream, wmm, mm);
    hipLaunchKernelGGL(k_quant_w, dim3(4096), dim3(256), 0, stream, weight, wq, sw);
    hipLaunchKernelGGL(k_quant_x, dim3(2048), dim3(256), 0, stream, x, mm, xq);
    hipLaunchKernelGGL(k_gemm, dim3(64 * 32), dim3(256), 0, stream,
                       xq, wq, sw, bias, mm, out);
}

// Round 7
// 465.854 us; speedup vs baseline: 1.2887x; 1.0298x over previous
//
#include <hip/hip_runtime.h>
#include <stdint.h>
#include <stddef.h>

// snnLinear: FWHT -> A4 global asym fake-quant -> W4 per-row sym fake-quant
// -> linear.  out[m,n] = sx*sw[n] * sum_k (qx-zp)*qw + bias[n], exact in i32.
//
// R3: LDS via generic float* -> scratch spill (197us/pass).
// R6: register/shfl FWHT ran ~135us/pass (DS-pipe bound) and was computed
//     TWICE. This round: compute FWHT once, store exact fp32 y into d_out
//     (free scratch, overwritten later by GEMM), stream-quantize from y.
//     GEMM: XOR-swizzle (pre-swizzled global source + swizzled ds_read,
//     rule-21) to kill the 8-way LDS bank conflict (1.68e7 cycles).

typedef __attribute__((ext_vector_type(4))) int int4v;
typedef __attribute__((ext_vector_type(4))) float float4v;

#define EPSQ 1e-8f

// lane l holds e[j] = row[(j>>2)*256 + l*4 + (j&3)], j=0..63.
// Reference stage order (element stride 2048 -> 1) maps to:
//   i-bits 11..8 : in-register j-strides 32,16,8,4
//   i-bits 7..2  : cross-lane shfl_xor masks 32,16,8,4,2,1
//   i-bits 1..0  : in-register j-strides 2,1
__device__ __forceinline__ void fwht_wave(float (&e)[64], int l) {
#pragma unroll
    for (int s = 32; s >= 4; s >>= 1)
#pragma unroll
        for (int j = 0; j < 64; ++j)
            if ((j & s) == 0) {
                float a = e[j], b = e[j + s];
                e[j] = a + b;
                e[j + s] = a - b;
            }
#pragma unroll
    for (int m = 32; m >= 1; m >>= 1) {
        float sgn = (l & m) ? -1.0f : 1.0f;
#pragma unroll
        for (int j = 0; j < 64; ++j) {
            float t = __shfl_xor(e[j], m);
            e[j] = fmaf(sgn, e[j], t);
        }
    }
#pragma unroll
    for (int s = 2; s >= 1; s >>= 1)
#pragma unroll
        for (int j = 0; j < 64; ++j)
            if ((j & s) == 0) {
                float a = e[j], b = e[j + s];
                e[j] = a + b;
                e[j + s] = a - b;
            }
}

// ---- pass 1: FWHT, store exact y (scaled), per-wave min/max --------------
__global__ __launch_bounds__(256) void k_fwht_store(
    const float* __restrict__ x, float* __restrict__ y,
    float2* __restrict__ wmm) {
    int l = threadIdx.x & 63, w = threadIdx.x >> 6;
    int row = blockIdx.x * 4 + w;
    const float4v* xv = (const float4v*)(x + (size_t)row * 4096);
    float e[64];
#pragma unroll
    for (int q = 0; q < 16; ++q) {
        float4v v = xv[q * 64 + l];
        e[4 * q + 0] = v[0]; e[4 * q + 1] = v[1];
        e[4 * q + 2] = v[2]; e[4 * q + 3] = v[3];
    }
    fwht_wave(e, l);
#pragma unroll
    for (int j = 0; j < 64; ++j) e[j] *= 0.015625f;  // 1/sqrt(4096), exact

    float4v* yv = (float4v*)(y + (size_t)row * 4096);
#pragma unroll
    for (int q = 0; q < 16; ++q) {
        float4v v;
        v[0] = e[4 * q + 0]; v[1] = e[4 * q + 1];
        v[2] = e[4 * q + 2]; v[3] = e[4 * q + 3];
        yv[q * 64 + l] = v;
    }
    float mn = e[0], mx = e[0];
#pragma unroll
    for (int j = 1; j < 64; ++j) { mn = fminf(mn, e[j]); mx = fmaxf(mx, e[j]); }
#pragma unroll
    for (int m = 32; m >= 1; m >>= 1) {
        mn = fminf(mn, __shfl_xor(mn, m));
        mx = fmaxf(mx, __shfl_xor(mx, m));
    }
    if (l == 0) wmm[row] = make_float2(mn, mx);
}

// ---- tiny deterministic reduction: 8192 wave-results -> global min/max ----
__global__ __launch_bounds__(256) void k_mmred(const float2* __restrict__ wmm,
                                               float* __restrict__ mm) {
    __shared__ float red[8];
    int t = threadIdx.x;
    float mn = INFINITY, mx = -INFINITY;
    for (int i = t; i < 8192; i += 256) {
        float2 v = wmm[i];
        mn = fminf(mn, v.x);
        mx = fmaxf(mx, v.y);
    }
#pragma unroll
    for (int m = 32; m >= 1; m >>= 1) {
        mn = fminf(mn, __shfl_xor(mn, m));
        mx = fmaxf(mx, __shfl_xor(mx, m));
    }
    if ((t & 63) == 0) { red[(t >> 6) * 2] = mn; red[(t >> 6) * 2 + 1] = mx; }
    __syncthreads();
    if (t == 0) {
#pragma unroll
        for (int wv = 1; wv < 4; ++wv) {
            mn = fminf(mn, red[wv * 2]);
            mx = fmaxf(mx, red[wv * 2 + 1]);
        }
        mm[0] = mn;
        mm[1] = mx;
    }
}

// ---- pass 2: streaming quantize y -> packed i8 codes (q - zp) ------------
__global__ __launch_bounds__(256) void k_quant_x(
    const float* __restrict__ y, const float* __restrict__ mm,
    int8_t* __restrict__ xq) {
    float xmin = mm[0], xmax = mm[1];
    float scale = fmaxf((xmax - xmin) / 15.0f, EPSQ);
    float zp = rintf(-xmin / scale);
    int izp = (int)zp;

    const float4v* yv = (const float4v*)y;
    int* q = (int*)xq;
    const size_t n4 = (size_t)8192 * 4096 / 4;
    const size_t stride = (size_t)2048 * 256;
    for (size_t i = (size_t)blockIdx.x * 256 + threadIdx.x; i < n4;
         i += stride) {
        float4v v = yv[i];
        int pk = 0;
#pragma unroll
        for (int r = 0; r < 4; ++r) {
            float qq = rintf(v[r] / scale) + zp;
            qq = fminf(fmaxf(qq, 0.0f), 15.0f);
            int code = (int)qq - izp;  // [-15,15]
            pk |= (code & 0xFF) << (8 * r);
        }
        q[i] = pk;
    }
}

// ---- weight quant: per-row absmax -> scale -> packed i8 ----
__global__ __launch_bounds__(256) void k_quant_w(
    const float* __restrict__ wgt, int8_t* __restrict__ wq,
    float* __restrict__ sw) {
    __shared__ float red[4];
    int o = blockIdx.x, t = threadIdx.x;
    const float4v* wv = (const float4v*)(wgt + (size_t)o * 4096);
    float4v a0 = wv[t * 4 + 0], a1 = wv[t * 4 + 1],
            a2 = wv[t * 4 + 2], a3 = wv[t * 4 + 3];
    float am = 0.0f;
#pragma unroll
    for (int r = 0; r < 4; ++r)
        am = fmaxf(am, fmaxf(fmaxf(fabsf(a0[r]), fabsf(a1[r])),
                             fmaxf(fabsf(a2[r]), fabsf(a3[r]))));
#pragma unroll
    for (int m = 32; m >= 1; m >>= 1) am = fmaxf(am, __shfl_xor(am, m));
    if ((t & 63) == 0) red[t >> 6] = am;
    __syncthreads();
    am = fmaxf(fmaxf(red[0], red[1]), fmaxf(red[2], red[3]));

    float scale = fmaxf(am / 7.0f, EPSQ);
    if (t == 0) sw[o] = scale;

    int4v pk;
#pragma unroll
    for (int k = 0; k < 4; ++k) {
        float4v a = (k == 0) ? a0 : (k == 1) ? a1 : (k == 2) ? a2 : a3;
        int p = 0;
#pragma unroll
        for (int r = 0; r < 4; ++r) {
            float q = rintf(a[r] / scale);
            q = fminf(fmaxf(q, -8.0f), 7.0f);
            p |= ((int)q & 0xFF) << (8 * r);
        }
        pk[k] = p;
    }
    *(int4v*)(wq + (size_t)o * 4096 + t * 16) = pk;
}

// ---------------- i8 GEMM, m97 structure + LDS XOR swizzle ----------------
// Swizzle (involution): 16B chunk cc of row r lives at LDS slot
// cc ^ ((r>>1)&3). gload_lds dest stays LINEAR; the global SOURCE chunk is
// pre-swizzled per lane (rule 21). ds_read applies the same XOR.
// Bank math: old read = 16 lanes -> banks {0,16} (8-way); new = 16 lanes
// cover all 32 banks start-slots {0,16,4,20,8,24,12,28} -> 2-way (free).
#define BM 128
#define BN 128
#define BKq 64

__global__ __launch_bounds__(256) void k_gemm(
    const int8_t* __restrict__ A,   // [8192][4096] qx-zp
    const int8_t* __restrict__ B,   // [4096][4096] qw (N x K)
    const float* __restrict__ sw, const float* __restrict__ bias,
    const float* __restrict__ mm, float* __restrict__ C) {
    constexpr int N = 4096, K = 4096;
    __shared__ __align__(16) int8_t As[BM * BKq];
    __shared__ __align__(16) int8_t Bs[BN * BKq];

    int tid = threadIdx.x;
    int m0 = (blockIdx.x >> 5) * BM;
    int n0 = (blockIdx.x & 31) * BN;
    int w = tid >> 6, l = tid & 63;
    int wr = w >> 1, wc = w & 1;  // wave -> 64x64 quadrant
    int kg = l >> 4, lr = l & 15;

    int4v acc[4][4] = {};

    for (int k0 = 0; k0 < K; k0 += BKq) {
#pragma unroll
        for (int it = 0; it < 2; ++it) {
            int idx = it * 256 + tid;
            int row = idx >> 2;
            int ccs = (idx & 3) ^ ((row >> 1) & 3);  // pre-swizzled source
            __builtin_amdgcn_global_load_lds(
                (const __attribute__((address_space(1))) void*)
                    (A + (size_t)(m0 + row) * K + k0 + ccs * 16),
                (__attribute__((address_space(3))) void*)(As + idx * 16),
                16, 0, 0);
            __builtin_amdgcn_global_load_lds(
                (const __attribute__((address_space(1))) void*)
                    (B + (size_t)(n0 + row) * K + k0 + ccs * 16),
                (__attribute__((address_space(3))) void*)(Bs + idx * 16),
                16, 0, 0);
        }
        __syncthreads();

        int4v af[4], bf[4];
#pragma unroll
        for (int i = 0; i < 4; ++i) {
            int ra = wr * 64 + i * 16 + lr;
            int rb = wc * 64 + i * 16 + lr;
            af[i] = *(const int4v*)(As + ra * BKq +
                                    ((kg ^ ((ra >> 1) & 3)) * 16));
            bf[i] = *(const int4v*)(Bs + rb * BKq +
                                    ((kg ^ ((rb >> 1) & 3)) * 16));
        }
#pragma unroll
        for (int i = 0; i < 4; ++i)
#pragma unroll
            for (int j = 0; j < 4; ++j)
                acc[i][j] = __builtin_amdgcn_mfma_i32_16x16x64_i8(
                    af[i], bf[j], acc[i][j], 0, 0, 0);
        __syncthreads();
    }

    float xmin = mm[0], xmax = mm[1];
    float sx = fmaxf((xmax - xmin) / 15.0f, EPSQ);

#pragma unroll
    for (int j = 0; j < 4; ++j) {
        int col = n0 + wc * 64 + j * 16 + lr;
        float s = sx * sw[col];
        float bz = bias[col];
#pragma unroll
        for (int i = 0; i < 4; ++i) {
            int rowb = m0 + wr * 64 + i * 16 + kg * 4;
#pragma unroll
            for (int r = 0; r < 4; ++r)
                C[(size_t)(rowb + r) * N + col] =
                    (float)acc[i][j][r] * s + bz;
        }
    }
}

extern "C" void kernel_launch(void* const* d_in, const int* in_sizes, int n_in,
                              void* d_out, int out_size, void* d_ws,
                              size_t ws_size, hipStream_t stream) {
    const float* x = (const float*)d_in[0];       // [4,2048,4096]
    const float* weight = (const float*)d_in[1];  // [4096,4096]
    const float* bias = (const float*)d_in[2];    // [4096]
    float* out = (float*)d_out;

    char* ws = (char*)d_ws;
    float* mm = (float*)ws;                            // 8 B  {min,max}
    float2* wmm = (float2*)(ws + 1024);                // 64 KB per-wave pairs
    float* sw = (float*)(ws + 131072);                 // 16 KB
    int8_t* xq = (int8_t*)(ws + (1 << 20));            // 32 MB
    int8_t* wq = (int8_t*)(ws + (1 << 20) + ((size_t)8192 * 4096));  // 16 MB

    // d_out doubles as the fp32 y buffer (exactly 8192*4096 floats):
    // written by k_fwht_store, read by k_quant_x, then overwritten by k_gemm.
    float* y = out;

    hipLaunchKernelGGL(k_fwht_store, dim3(2048), dim3(256), 0, stream,
                       x, y, wmm);
    hipLaunchKernelGGL(k_mmred, dim3(1), dim3(256), 0, stream, wmm, mm);
    hipLaunchKernelGGL(k_quant_w, dim3(4096), dim3(256), 0, stream,
                       weight, wq, sw);
    hipLaunchKernelGGL(k_quant_x, dim3(2048), dim3(256), 0, stream,
                       y, mm, xq);
    hipLaunchKernelGGL(k_gemm, dim3(64 * 32), dim3(256), 0, stream,
                       xq, wq, sw, bias, mm, out);
}